// Round 9
// baseline (806.663 us; speedup 1.0000x reference)
//
#include <hip/hip_runtime.h>
#include <stdint.h>

#define NSTEPS 40

typedef float    floatx4  __attribute__((ext_vector_type(4)));
typedef __bf16   bf16x8   __attribute__((ext_vector_type(8)));
typedef uint32_t uint32x2 __attribute__((ext_vector_type(2)));

__device__ __forceinline__ __bf16 f2bf(float f){
  union { float f; uint32_t u; } v; v.f = f;
  uint32_t r = v.u + 0x7FFFu + ((v.u >> 16) & 1u);   // RNE (prep kernel only)
  union { uint16_t s; __bf16 b; } o; o.s = (uint16_t)(r >> 16);
  return o.b;
}
__device__ __forceinline__ float bf2f(__bf16 b){
  union { uint16_t s; __bf16 b; } i; i.b = b;
  union { uint32_t u; float f; } o; o.u = ((uint32_t)i.s) << 16;
  return o.f;
}
// HW packed f32x2 -> bf16x2 (RNE), 1 instruction
__device__ __forceinline__ uint32_t cvt_pk_bf16(float lo, float hi){
  uint32_t d;
  asm("v_cvt_pk_bf16_f32 %0, %1, %2" : "=v"(d) : "v"(lo), "v"(hi));
  return d;
}
__device__ __forceinline__ float fast_tanh(float x){
  float e = __expf(2.0f * x);
  return __builtin_fmaf(-2.0f, __builtin_amdgcn_rcpf(e + 1.0f), 1.0f);
}

// ---- prep: bf16-cast + transpose weights into workspace (proven) ----
__global__ void prep_kernel(const float* __restrict__ Ws,
                            const float* __restrict__ W1,
                            const float* __restrict__ W2,
                            __bf16* __restrict__ WsT,
                            __bf16* __restrict__ W1T,
                            __bf16* __restrict__ W2T){
  int tid = blockIdx.x * blockDim.x + threadIdx.x;
  int stride = gridDim.x * blockDim.x;
  for (int i = tid; i < 512*256; i += stride){
    int k = i >> 8, n = i & 255;
    WsT[n*512 + k] = f2bf(Ws[i]);
  }
  for (int i = tid; i < 256*256; i += stride){
    int k = i >> 8, n = i & 255;
    W1T[n*256 + k] = f2bf(W1[i]);
    W2T[n*256 + k] = f2bf(W2[i]);
  }
}

// Fused ODE kernel, round 9: SOFTWARE-PIPELINED DUAL STREAMS.
// r7/r8 evidence: MfmaUtil 39 + VALUBusy 44 + LDS ~65%, none saturated --
// barriers phase-lock all waves, so runtime = sum of (GEMM phase + tanh phase
// + barrier drain). Fix: split the 32 batch rows into two independent 16-row
// streams P,Q offset by half an eval; every barrier interval pairs one
// stream's GEMM (MFMA) with the other's tanh/pack/write (VALU) -> pipes and
// the 2 waves/SIMD overlap. Same registers (accum split 48 regs), same
// weights (128, shared), same swizzle, bit-identical per-row math.
// Interval layout per eval i (4 barriers):
//   I1: P.writeH(i)   | Q.gemm2(i-1)   I2: P.gemm1(i) | Q.writeH(i)
//   I3: P.tanh(i)     | Q.gemm1(i)     I4: P.gemm2(i) | Q.tanh(i)
// Buffers: sb[0]=P_h, sb[1]=P_z, sb[2]=Q_h, sb[3]=Q_z (8 KB each).
__global__ __launch_bounds__(512, 2)
void ode_kernel(const float* __restrict__ x,
                const float* __restrict__ b_state,
                const float* __restrict__ W1full,   // 257x256 fp32 (row 256 = t row)
                const float* __restrict__ b1,
                const float* __restrict__ b2,
                const float* __restrict__ Wout,     // 256x18 fp32
                const float* __restrict__ bout,
                const __bf16* __restrict__ WsT,     // [256][512]
                const __bf16* __restrict__ W1Tg,    // [256][256]
                const __bf16* __restrict__ W2Tg,    // [256][256]
                float* __restrict__ out)
{
  __shared__ __align__(16) __bf16 lds_sb[4][16*256]; // 32 KB total
  __shared__ __align__(16) float  lds_bias[3*256];   //  3 KB  b1 | w_t | b2

  const int tid  = threadIdx.x;
  const int wave = tid >> 6;       // 0..7
  const int lane = tid & 63;
  const int c16  = lane & 15;      // batch row within stream / A-row low bits
  const int q    = lane >> 4;      // 0..3 (MFMA quad)
  const int nh0  = wave * 32;      // this wave's hid-row base (32 rows)
  const int m0   = blockIdx.x * 32;

  if (tid < 256){
    lds_bias[tid]       = b1[tid];
    lds_bias[256 + tid] = W1full[256*256 + tid];  // time row of W_dyn1
    lds_bias[512 + tid] = b2[tid];
  }

  // ---- per-lane addressing (16-row XOR chunk swizzle; key = batch row) ----
  int arow[2];
  #pragma unroll
  for (int mt = 0; mt < 2; ++mt) arow[mt] = nh0 + mt*16 + c16;
  const int brow = c16 * 256;       // B batch row base
  const int bkey = c16;             // swizzle key (0..15)
  int woff[2];                      // C/D write offsets (8B, chunk-swizzled)
  #pragma unroll
  for (int mt = 0; mt < 2; ++mt){
    int n0 = nh0 + mt*16 + 4*q;
    woff[mt] = brow + (((n0 >> 3) ^ bkey) << 3) + (n0 & 7);
  }
  const int bidx = nh0 + 4*q;       // bias row base (add mt*16)

  // ---- resident weight fragments: W1^T, W2^T (A-operands), 128 regs ----
  bf16x8 w1f[2][8], w2f[2][8];
  #pragma unroll
  for (int mt = 0; mt < 2; ++mt)
    #pragma unroll
    for (int kt = 0; kt < 8; ++kt){
      w1f[mt][kt] = *(const bf16x8*)&W1Tg[arow[mt]*256 + kt*32 + q*8];
      w2f[mt][kt] = *(const bf16x8*)&W2Tg[arow[mt]*256 + kt*32 + q*8];
    }
  #pragma unroll
  for (int mt = 0; mt < 2; ++mt)
    #pragma unroll
    for (int kt = 0; kt < 8; ++kt)
      asm volatile("" : "+v"(w1f[mt][kt]), "+v"(w2f[mt][kt]));

  const float dt  = 1.0f / NSTEPS;
  const float hdt = 0.5f * dt;
  const float dt6 = dt / 6.0f;
  const floatx4 vzero = {0.f, 0.f, 0.f, 0.f};

  floatx4 gP[2], hvP[2], smP[2], gQ[2], hvQ[2], smQ[2];
  #pragma unroll
  for (int mt = 0; mt < 2; ++mt){
    gP[mt] = vzero; smP[mt] = vzero; gQ[mt] = vzero; smQ[mt] = vzero;
  }

  // ---- phase 0: h0^T = tanh(Ws^T @ x^T + b_state), both streams ----
  {
    floatx4 aP[2], aQ[2];
    #pragma unroll
    for (int mt = 0; mt < 2; ++mt){
      floatx4 bsv;
      #pragma unroll
      for (int r = 0; r < 4; ++r) bsv[r] = b_state[nh0 + mt*16 + 4*q + r];
      aP[mt] = bsv; aQ[mt] = bsv;
    }
    #pragma unroll 2
    for (int kt = 0; kt < 16; ++kt){
      bf16x8 bP, bQ;
      {
        const float* px = &x[(size_t)(m0 + c16)*512 + kt*32 + q*8];
        floatx4 f0 = *(const floatx4*)px;
        floatx4 f1 = *(const floatx4*)(px + 4);
        union { uint32_t u[4]; bf16x8 v; } pk;
        pk.u[0] = cvt_pk_bf16(f0[0], f0[1]);
        pk.u[1] = cvt_pk_bf16(f0[2], f0[3]);
        pk.u[2] = cvt_pk_bf16(f1[0], f1[1]);
        pk.u[3] = cvt_pk_bf16(f1[2], f1[3]);
        bP = pk.v;
      }
      {
        const float* px = &x[(size_t)(m0 + 16 + c16)*512 + kt*32 + q*8];
        floatx4 f0 = *(const floatx4*)px;
        floatx4 f1 = *(const floatx4*)(px + 4);
        union { uint32_t u[4]; bf16x8 v; } pk;
        pk.u[0] = cvt_pk_bf16(f0[0], f0[1]);
        pk.u[1] = cvt_pk_bf16(f0[2], f0[3]);
        pk.u[2] = cvt_pk_bf16(f1[0], f1[1]);
        pk.u[3] = cvt_pk_bf16(f1[2], f1[3]);
        bQ = pk.v;
      }
      #pragma unroll
      for (int mt = 0; mt < 2; ++mt){
        bf16x8 a = *(const bf16x8*)&WsT[arow[mt]*512 + kt*32 + q*8];
        aP[mt] = __builtin_amdgcn_mfma_f32_16x16x32_bf16(a, bP, aP[mt], 0, 0, 0);
        aQ[mt] = __builtin_amdgcn_mfma_f32_16x16x32_bf16(a, bQ, aQ[mt], 0, 0, 0);
      }
    }
    #pragma unroll
    for (int mt = 0; mt < 2; ++mt)
      #pragma unroll
      for (int r = 0; r < 4; ++r){
        hvP[mt][r] = fast_tanh(aP[mt][r]);
        hvQ[mt][r] = fast_tanh(aQ[mt][r]);
      }
  }

  // ---- pipeline stage helpers (fully inlined; all indices compile-time) ----
  auto stage_W = [&](floatx4 (&g)[2], floatx4 (&hv)[2], __bf16* sb, float cin){
    #pragma unroll
    for (int mt = 0; mt < 2; ++mt){
      float v0 = __builtin_fmaf(cin, g[mt][0], hv[mt][0]);
      float v1 = __builtin_fmaf(cin, g[mt][1], hv[mt][1]);
      float v2 = __builtin_fmaf(cin, g[mt][2], hv[mt][2]);
      float v3 = __builtin_fmaf(cin, g[mt][3], hv[mt][3]);
      uint32x2 wv = { cvt_pk_bf16(v0, v1), cvt_pk_bf16(v2, v3) };
      *(uint32x2*)&sb[woff[mt]] = wv;
    }
  };
  auto stage_G1 = [&](floatx4 (&g)[2], const __bf16* sb, float te){
    #pragma unroll
    for (int mt = 0; mt < 2; ++mt){
      floatx4 b1v = *(const floatx4*)&lds_bias[bidx + mt*16];
      floatx4 wtv = *(const floatx4*)&lds_bias[256 + bidx + mt*16];
      #pragma unroll
      for (int r = 0; r < 4; ++r) g[mt][r] = __builtin_fmaf(te, wtv[r], b1v[r]);
    }
    #pragma unroll
    for (int kt = 0; kt < 8; ++kt){
      bf16x8 b = *(const bf16x8*)&sb[brow + (((kt*4 + q) ^ bkey) << 3)];
      #pragma unroll
      for (int mt = 0; mt < 2; ++mt)
        g[mt] = __builtin_amdgcn_mfma_f32_16x16x32_bf16(w1f[mt][kt], b, g[mt], 0, 0, 0);
    }
  };
  auto stage_T = [&](floatx4 (&g)[2], __bf16* sb){
    #pragma unroll
    for (int mt = 0; mt < 2; ++mt){
      float v0 = fast_tanh(g[mt][0]);
      float v1 = fast_tanh(g[mt][1]);
      float v2 = fast_tanh(g[mt][2]);
      float v3 = fast_tanh(g[mt][3]);
      uint32x2 wv = { cvt_pk_bf16(v0, v1), cvt_pk_bf16(v2, v3) };
      *(uint32x2*)&sb[woff[mt]] = wv;
    }
  };
  auto stage_G2 = [&](floatx4 (&g)[2], floatx4 (&hv)[2], floatx4 (&sm)[2],
                      const __bf16* sb, float we, bool fin){
    #pragma unroll
    for (int mt = 0; mt < 2; ++mt)
      g[mt] = *(const floatx4*)&lds_bias[512 + bidx + mt*16];
    #pragma unroll
    for (int kt = 0; kt < 8; ++kt){
      bf16x8 b = *(const bf16x8*)&sb[brow + (((kt*4 + q) ^ bkey) << 3)];
      #pragma unroll
      for (int mt = 0; mt < 2; ++mt)
        g[mt] = __builtin_amdgcn_mfma_f32_16x16x32_bf16(w2f[mt][kt], b, g[mt], 0, 0, 0);
    }
    #pragma unroll
    for (int mt = 0; mt < 2; ++mt)
      #pragma unroll
      for (int r = 0; r < 4; ++r)
        sm[mt][r] = __builtin_fmaf(we, g[mt][r], sm[mt][r]);
    if (fin){
      #pragma unroll
      for (int mt = 0; mt < 2; ++mt){
        #pragma unroll
        for (int r = 0; r < 4; ++r)
          hv[mt][r] = __builtin_fmaf(dt6, sm[mt][r], hv[mt][r]);
        sm[mt] = vzero;
      }
    }
  };

  // ---- pipelined main loop: flat eval index i, Q lags P by half an eval ----
  #pragma unroll 1
  for (int i = 0; i < NSTEPS*4; ++i){
    const int e = i & 3;
    const float cf = (e == 0) ? 0.f : ((e == 3) ? dt : hdt);  // = cin = t-offset
    const float te = dt * (float)(i >> 2) + cf;
    const float we = (e == 1 || e == 2) ? 2.f : 1.f;
    const int ep = (i - 1) & 3;
    const float wep = (ep == 1 || ep == 2) ? 2.f : 1.f;

    // I1: P writes h_eval(i); Q finishes eval i-1 (GEMM2 + rk4)
    stage_W(gP, hvP, lds_sb[0], cf);
    if (i) stage_G2(gQ, hvQ, smQ, lds_sb[3], wep, ep == 3);
    __syncthreads();
    // I2: P GEMM1(i); Q writes h_eval(i)
    stage_G1(gP, lds_sb[0], te);
    stage_W(gQ, hvQ, lds_sb[2], cf);
    __syncthreads();
    // I3: P tanh->z(i); Q GEMM1(i)
    stage_T(gP, lds_sb[1]);
    stage_G1(gQ, lds_sb[2], te);
    __syncthreads();
    // I4: P GEMM2+rk4(i); Q tanh->z(i)
    stage_G2(gP, hvP, smP, lds_sb[1], we, e == 3);
    stage_T(gQ, lds_sb[3]);
    __syncthreads();
  }
  // drain: Q's final GEMM2 (eval NSTEPS*4-1: e==3 -> we=1, fin)
  stage_G2(gQ, hvQ, smQ, lds_sb[3], 1.f, true);

  // ---- epilogue: final h -> sb[0] (P) / sb[2] (Q); out = h @ Wout + bout ----
  stage_W(gP, hvP, lds_sb[0], 0.f);
  stage_W(gQ, hvQ, lds_sb[2], 0.f);
  __syncthreads();
  {
    const int r  = tid & 31;         // batch row within block
    const int og = tid >> 5;         // 16 groups; first 6 cover 18 outputs
    if (og < 6){
      const int obase = og * 3;
      const int sbi = (r >> 4) * 2;  // 0 (P) or 2 (Q)
      const int rr  = r & 15;
      float acc[3] = {0.f, 0.f, 0.f};
      for (int c = 0; c < 32; ++c){
        bf16x8 h8 = *(const bf16x8*)&lds_sb[sbi][rr*256 + ((c ^ rr) << 3)];
        #pragma unroll
        for (int j = 0; j < 8; ++j){
          float hval = bf2f(h8[j]);
          int kk = c*8 + j;
          #pragma unroll
          for (int oo = 0; oo < 3; ++oo)
            acc[oo] += hval * Wout[kk*18 + obase + oo];
        }
      }
      #pragma unroll
      for (int oo = 0; oo < 3; ++oo)
        out[(size_t)(m0 + r)*18 + obase + oo] = acc[oo] + bout[obase + oo];
    }
  }
}

extern "C" void kernel_launch(void* const* d_in, const int* in_sizes, int n_in,
                              void* d_out, int out_size, void* d_ws, size_t ws_size,
                              hipStream_t stream){
  const float* x   = (const float*)d_in[0];
  const float* Ws  = (const float*)d_in[1];
  const float* bs  = (const float*)d_in[2];
  const float* W1  = (const float*)d_in[3];
  const float* b1  = (const float*)d_in[4];
  const float* W2  = (const float*)d_in[5];
  const float* b2  = (const float*)d_in[6];
  const float* Wo  = (const float*)d_in[7];
  const float* bo  = (const float*)d_in[8];
  float* out = (float*)d_out;

  __bf16* WsT = (__bf16*)d_ws;          // 256x512 bf16 = 256 KB
  __bf16* W1T = WsT + 512*256;          // 256x256 bf16 = 128 KB
  __bf16* W2T = W1T + 256*256;          // 256x256 bf16 = 128 KB

  prep_kernel<<<128, 256, 0, stream>>>(Ws, W1, W2, WsT, W1T, W2T);
  ode_kernel<<<512, 512, 0, stream>>>(x, bs, W1, b1, b2, Wo, bo, WsT, W1T, W2T, out);
}

// Round 10
// 711.359 us; speedup vs baseline: 1.1340x; 1.1340x over previous
//
#include <hip/hip_runtime.h>
#include <stdint.h>

#define NSTEPS 40
#define SBS 264   // LDS state-row stride in elements (256 + 8 pad; 528 B, 16B-aligned)

typedef float    floatx4  __attribute__((ext_vector_type(4)));
typedef __bf16   bf16x8   __attribute__((ext_vector_type(8)));
typedef uint32_t uint32x2 __attribute__((ext_vector_type(2)));

__device__ __forceinline__ __bf16 f2bf(float f){
  union { float f; uint32_t u; } v; v.f = f;
  uint32_t r = v.u + 0x7FFFu + ((v.u >> 16) & 1u);   // RNE (prep kernel only)
  union { uint16_t s; __bf16 b; } o; o.s = (uint16_t)(r >> 16);
  return o.b;
}
__device__ __forceinline__ float bf2f(__bf16 b){
  union { uint16_t s; __bf16 b; } i; i.b = b;
  union { uint32_t u; float f; } o; o.u = ((uint32_t)i.s) << 16;
  return o.f;
}
// HW packed f32x2 -> bf16x2 (RNE), 1 instruction
__device__ __forceinline__ uint32_t cvt_pk_bf16(float lo, float hi){
  uint32_t d;
  asm("v_cvt_pk_bf16_f32 %0, %1, %2" : "=v"(d) : "v"(lo), "v"(hi));
  return d;
}
__device__ __forceinline__ float fast_tanh(float x){
  float e = __expf(2.0f * x);
  return __builtin_fmaf(-2.0f, __builtin_amdgcn_rcpf(e + 1.0f), 1.0f);
}

// ---- prep: bf16-cast + transpose weights into workspace (proven) ----
__global__ void prep_kernel(const float* __restrict__ Ws,
                            const float* __restrict__ W1,
                            const float* __restrict__ W2,
                            __bf16* __restrict__ WsT,
                            __bf16* __restrict__ W1T,
                            __bf16* __restrict__ W2T){
  int tid = blockIdx.x * blockDim.x + threadIdx.x;
  int stride = gridDim.x * blockDim.x;
  for (int i = tid; i < 512*256; i += stride){
    int k = i >> 8, n = i & 255;
    WsT[n*512 + k] = f2bf(Ws[i]);
  }
  for (int i = tid; i < 256*256; i += stride){
    int k = i >> 8, n = i & 255;
    W1T[n*256 + k] = f2bf(W1[i]);
    W2T[n*256 + k] = f2bf(W2[i]);
  }
}

// Fused ODE kernel, round 10: ONE-ROUND GRID. 256 blocks x 64 batch rows,
// 512 threads = 8 waves @ 2 waves/SIMD. Exactly 1 block/CU -> per-CU barrier
// count HALVES vs r7's 2 sequential block-rounds (320 vs 640 drains); per-CU
// MFMA/VALU/LDS totals are invariant. (r9 showed interleaving with the same
// barrier count regresses; barriers-per-CU is the lever.)
// Each wave owns 32 hid rows (mt=2, weights 128 regs resident); batch nt=4.
// Register diet to fit ~256 unified regs at 2 waves/SIMD: accum 96 (hv/sm/g)
// + weights 128 + transient temps; addresses recomputed from 2 base regs.
// State buffers padded-linear (SBS=264, r7-proven faster than swizzle).
// 2 barriers per eval (SB0=h_eval, SB1=z).
__global__ __launch_bounds__(512, 2)
void ode_kernel(const float* __restrict__ x,
                const float* __restrict__ b_state,
                const float* __restrict__ W1full,   // 257x256 fp32 (row 256 = t row)
                const float* __restrict__ b1,
                const float* __restrict__ b2,
                const float* __restrict__ Wout,     // 256x18 fp32
                const float* __restrict__ bout,
                const __bf16* __restrict__ WsT,     // [256][512]
                const __bf16* __restrict__ W1Tg,    // [256][256]
                const __bf16* __restrict__ W2Tg,    // [256][256]
                float* __restrict__ out)
{
  __shared__ __align__(16) __bf16 lds_sb0[64*SBS];  // 33 KB  h_eval
  __shared__ __align__(16) __bf16 lds_sb1[64*SBS];  // 33 KB  z
  __shared__ __align__(16) float  lds_bias[3*256];  //  3 KB  b1 | w_t | b2

  const int tid  = threadIdx.x;
  const int wave = tid >> 6;       // 0..7
  const int lane = tid & 63;
  const int c16  = lane & 15;      // MFMA col / A-row low bits
  const int q    = lane >> 4;      // 0..3 (MFMA quad)
  const int nh0  = wave * 32;      // this wave's hid-row base (32 rows)
  const int m0   = blockIdx.x * 64;

  if (tid < 256){
    lds_bias[tid]       = b1[tid];
    lds_bias[256 + tid] = W1full[256*256 + tid];  // time row of W_dyn1
    lds_bias[512 + tid] = b2[tid];
  }

  // ---- per-lane addressing (padded-linear; minimal resident regs) ----
  int arow[2];
  #pragma unroll
  for (int mt = 0; mt < 2; ++mt) arow[mt] = nh0 + mt*16 + c16;
  const int browc = c16 * SBS;      // B batch-row base for nt=0; nt adds 16*SBS
  const int n04   = nh0 + 4*q;      // C/D hid base; mt adds 16
  const int bidx  = n04;            // bias row base (add mt*16)

  // ---- resident weight fragments: W1^T, W2^T (A-operands), 128 regs ----
  bf16x8 w1f[2][8], w2f[2][8];
  #pragma unroll
  for (int mt = 0; mt < 2; ++mt)
    #pragma unroll
    for (int kt = 0; kt < 8; ++kt){
      w1f[mt][kt] = *(const bf16x8*)&W1Tg[arow[mt]*256 + kt*32 + q*8];
      w2f[mt][kt] = *(const bf16x8*)&W2Tg[arow[mt]*256 + kt*32 + q*8];
    }
  #pragma unroll
  for (int mt = 0; mt < 2; ++mt)
    #pragma unroll
    for (int kt = 0; kt < 8; ++kt)
      asm volatile("" : "+v"(w1f[mt][kt]), "+v"(w2f[mt][kt]));

  floatx4 g[2][4], hv[2][4];       // [hid-tile mt][batch-tile nt]

  // ---- phase 0: h0^T = tanh(Ws^T @ x^T + b_state) ----
  {
    #pragma unroll
    for (int mt = 0; mt < 2; ++mt){
      floatx4 bsv;
      #pragma unroll
      for (int r = 0; r < 4; ++r) bsv[r] = b_state[nh0 + mt*16 + 4*q + r];
      #pragma unroll
      for (int nt = 0; nt < 4; ++nt) g[mt][nt] = bsv;
    }
    #pragma unroll 1
    for (int kt = 0; kt < 16; ++kt){
      bf16x8 b[4];
      #pragma unroll
      for (int nt = 0; nt < 4; ++nt){
        const float* px = &x[(size_t)(m0 + nt*16 + c16)*512 + kt*32 + q*8];
        floatx4 f0 = *(const floatx4*)px;
        floatx4 f1 = *(const floatx4*)(px + 4);
        union { uint32_t u[4]; bf16x8 v; } pk;
        pk.u[0] = cvt_pk_bf16(f0[0], f0[1]);
        pk.u[1] = cvt_pk_bf16(f0[2], f0[3]);
        pk.u[2] = cvt_pk_bf16(f1[0], f1[1]);
        pk.u[3] = cvt_pk_bf16(f1[2], f1[3]);
        b[nt] = pk.v;
      }
      #pragma unroll
      for (int mt = 0; mt < 2; ++mt){
        bf16x8 a = *(const bf16x8*)&WsT[arow[mt]*512 + kt*32 + q*8];
        #pragma unroll
        for (int nt = 0; nt < 4; ++nt)
          g[mt][nt] = __builtin_amdgcn_mfma_f32_16x16x32_bf16(a, b[nt], g[mt][nt], 0, 0, 0);
      }
    }
    #pragma unroll
    for (int mt = 0; mt < 2; ++mt)
      #pragma unroll
      for (int nt = 0; nt < 4; ++nt)
        #pragma unroll
        for (int r = 0; r < 4; ++r)
          hv[mt][nt][r] = fast_tanh(g[mt][nt][r]);
  }

  const float dt  = 1.0f / NSTEPS;
  const float dt6 = dt / 6.0f;
  const floatx4 vzero = {0.f, 0.f, 0.f, 0.f};

  #pragma unroll 1
  for (int s = 0; s < NSTEPS; ++s){
    float tbase = dt * (float)s;
    floatx4 sm[2][4];
    #pragma unroll
    for (int mt = 0; mt < 2; ++mt)
      #pragma unroll
      for (int nt = 0; nt < 4; ++nt)
        sm[mt][nt] = vzero;

    #pragma unroll 1
    for (int e = 0; e < 4; ++e){
      float half_or_full = (e == 3) ? dt : 0.5f * dt;
      float cin = (e == 0) ? 0.0f : half_or_full;   // h_eval = h + cin*k_prev
      float te  = tbase + ((e == 0) ? 0.0f : half_or_full);
      float we  = (e == 1 || e == 2) ? 2.0f : 1.0f;

      // write h_eval -> SB0 (g = k_{e-1}; cin=0 at e=0).
      #pragma unroll
      for (int mt = 0; mt < 2; ++mt)
        #pragma unroll
        for (int nt = 0; nt < 4; ++nt){
          float v0 = __builtin_fmaf(cin, g[mt][nt][0], hv[mt][nt][0]);
          float v1 = __builtin_fmaf(cin, g[mt][nt][1], hv[mt][nt][1]);
          float v2 = __builtin_fmaf(cin, g[mt][nt][2], hv[mt][nt][2]);
          float v3 = __builtin_fmaf(cin, g[mt][nt][3], hv[mt][nt][3]);
          uint32x2 wv = { cvt_pk_bf16(v0, v1), cvt_pk_bf16(v2, v3) };
          *(uint32x2*)&lds_sb0[browc + nt*(16*SBS) + n04 + mt*16] = wv;
        }
      __syncthreads();   // barrier A

      // GEMM1: z^T = W1^T @ h_eval^T (+ b1 + t*w_t); A resident in regs
      #pragma unroll
      for (int mt = 0; mt < 2; ++mt){
        floatx4 b1v = *(const floatx4*)&lds_bias[bidx + mt*16];
        floatx4 wtv = *(const floatx4*)&lds_bias[256 + bidx + mt*16];
        floatx4 bias;
        #pragma unroll
        for (int r = 0; r < 4; ++r) bias[r] = __builtin_fmaf(te, wtv[r], b1v[r]);
        #pragma unroll
        for (int nt = 0; nt < 4; ++nt) g[mt][nt] = bias;
      }
      #pragma unroll
      for (int kt = 0; kt < 8; ++kt){
        bf16x8 b[4];
        #pragma unroll
        for (int nt = 0; nt < 4; ++nt)
          b[nt] = *(const bf16x8*)&lds_sb0[browc + nt*(16*SBS) + kt*32 + q*8];
        #pragma unroll
        for (int mt = 0; mt < 2; ++mt)
          #pragma unroll
          for (int nt = 0; nt < 4; ++nt)
            g[mt][nt] = __builtin_amdgcn_mfma_f32_16x16x32_bf16(w1f[mt][kt], b[nt], g[mt][nt], 0, 0, 0);
      }

      // z = tanh(.) -> SB1
      #pragma unroll
      for (int mt = 0; mt < 2; ++mt)
        #pragma unroll
        for (int nt = 0; nt < 4; ++nt){
          float v0 = fast_tanh(g[mt][nt][0]);
          float v1 = fast_tanh(g[mt][nt][1]);
          float v2 = fast_tanh(g[mt][nt][2]);
          float v3 = fast_tanh(g[mt][nt][3]);
          uint32x2 wv = { cvt_pk_bf16(v0, v1), cvt_pk_bf16(v2, v3) };
          *(uint32x2*)&lds_sb1[browc + nt*(16*SBS) + n04 + mt*16] = wv;
        }
      __syncthreads();   // barrier B

      // GEMM2: k^T = W2^T @ z^T (+b2); A resident in regs
      #pragma unroll
      for (int mt = 0; mt < 2; ++mt){
        floatx4 b2v = *(const floatx4*)&lds_bias[512 + bidx + mt*16];
        #pragma unroll
        for (int nt = 0; nt < 4; ++nt) g[mt][nt] = b2v;
      }
      #pragma unroll
      for (int kt = 0; kt < 8; ++kt){
        bf16x8 b[4];
        #pragma unroll
        for (int nt = 0; nt < 4; ++nt)
          b[nt] = *(const bf16x8*)&lds_sb1[browc + nt*(16*SBS) + kt*32 + q*8];
        #pragma unroll
        for (int mt = 0; mt < 2; ++mt)
          #pragma unroll
          for (int nt = 0; nt < 4; ++nt)
            g[mt][nt] = __builtin_amdgcn_mfma_f32_16x16x32_bf16(w2f[mt][kt], b[nt], g[mt][nt], 0, 0, 0);
      }

      // RK4 sum
      #pragma unroll
      for (int mt = 0; mt < 2; ++mt)
        #pragma unroll
        for (int nt = 0; nt < 4; ++nt)
          #pragma unroll
          for (int r = 0; r < 4; ++r)
            sm[mt][nt][r] = __builtin_fmaf(we, g[mt][nt][r], sm[mt][nt][r]);
    } // evals

    #pragma unroll
    for (int mt = 0; mt < 2; ++mt)
      #pragma unroll
      for (int nt = 0; nt < 4; ++nt)
        #pragma unroll
        for (int r = 0; r < 4; ++r)
          hv[mt][nt][r] = __builtin_fmaf(dt6, sm[mt][nt][r], hv[mt][nt][r]);
  } // steps

  // ---- epilogue: h_T -> SB0, then out = h_T @ Wout + bout ----
  #pragma unroll
  for (int mt = 0; mt < 2; ++mt)
    #pragma unroll
    for (int nt = 0; nt < 4; ++nt){
      uint32x2 wv = { cvt_pk_bf16(hv[mt][nt][0], hv[mt][nt][1]),
                      cvt_pk_bf16(hv[mt][nt][2], hv[mt][nt][3]) };
      *(uint32x2*)&lds_sb0[browc + nt*(16*SBS) + n04 + mt*16] = wv;
    }
  __syncthreads();
  {
    const int r  = tid & 63;         // batch row within block (0..63)
    const int og = tid >> 6;         // 8 groups; first 6 cover 18 outputs
    if (og < 6){
      const int obase = og * 3;
      float acc[3] = {0.f, 0.f, 0.f};
      for (int c = 0; c < 32; ++c){
        bf16x8 h8 = *(const bf16x8*)&lds_sb0[r*SBS + c*8];
        #pragma unroll
        for (int j = 0; j < 8; ++j){
          float hval = bf2f(h8[j]);
          int kk = c*8 + j;
          #pragma unroll
          for (int oo = 0; oo < 3; ++oo)
            acc[oo] += hval * Wout[kk*18 + obase + oo];
        }
      }
      #pragma unroll
      for (int oo = 0; oo < 3; ++oo)
        out[(size_t)(m0 + r)*18 + obase + oo] = acc[oo] + bout[obase + oo];
    }
  }
}

extern "C" void kernel_launch(void* const* d_in, const int* in_sizes, int n_in,
                              void* d_out, int out_size, void* d_ws, size_t ws_size,
                              hipStream_t stream){
  const float* x   = (const float*)d_in[0];
  const float* Ws  = (const float*)d_in[1];
  const float* bs  = (const float*)d_in[2];
  const float* W1  = (const float*)d_in[3];
  const float* b1  = (const float*)d_in[4];
  const float* W2  = (const float*)d_in[5];
  const float* b2  = (const float*)d_in[6];
  const float* Wo  = (const float*)d_in[7];
  const float* bo  = (const float*)d_in[8];
  float* out = (float*)d_out;

  __bf16* WsT = (__bf16*)d_ws;          // 256x512 bf16 = 256 KB
  __bf16* W1T = WsT + 512*256;          // 256x256 bf16 = 128 KB
  __bf16* W2T = W1T + 256*256;          // 256x256 bf16 = 128 KB

  prep_kernel<<<128, 256, 0, stream>>>(Ws, W1, W2, WsT, W1T, W2T);
  ode_kernel<<<256, 512, 0, stream>>>(x, bs, W1, b1, b2, Wo, bo, WsT, W1T, W2T, out);
}

// Round 11
// 574.368 us; speedup vs baseline: 1.4044x; 1.2385x over previous
//
#include <hip/hip_runtime.h>
#include <stdint.h>

#define NSTEPS 40
#define SBS 264   // LDS state-row stride in elements (256 + 8 pad; 528 B, 16B-aligned)

typedef float    floatx4  __attribute__((ext_vector_type(4)));
typedef __bf16   bf16x8   __attribute__((ext_vector_type(8)));
typedef __bf16   bf16x4   __attribute__((ext_vector_type(4)));
typedef uint32_t uint32x2 __attribute__((ext_vector_type(2)));

__device__ __forceinline__ __bf16 f2bf(float f){
  union { float f; uint32_t u; } v; v.f = f;
  uint32_t r = v.u + 0x7FFFu + ((v.u >> 16) & 1u);   // RNE (prep kernels only)
  union { uint16_t s; __bf16 b; } o; o.s = (uint16_t)(r >> 16);
  return o.b;
}
__device__ __forceinline__ float bf2f(__bf16 b){
  union { uint16_t s; __bf16 b; } i; i.b = b;
  union { uint32_t u; float f; } o; o.u = ((uint32_t)i.s) << 16;
  return o.f;
}
__device__ __forceinline__ uint32_t cvt_pk_bf16(float lo, float hi){
  uint32_t d;
  asm("v_cvt_pk_bf16_f32 %0, %1, %2" : "=v"(d) : "v"(lo), "v"(hi));
  return d;
}
__device__ __forceinline__ float fast_tanh(float x){
  float e = __expf(2.0f * x);
  return __builtin_fmaf(-2.0f, __builtin_amdgcn_rcpf(e + 1.0f), 1.0f);
}

// ---- prep1: bf16-cast + transpose weights; beta = b2 @ W1 (fp32) ----
__global__ void prep_kernel(const float* __restrict__ Ws,
                            const float* __restrict__ W1,
                            const float* __restrict__ W2,
                            const float* __restrict__ b2,
                            __bf16* __restrict__ WsT,
                            __bf16* __restrict__ W1T,
                            __bf16* __restrict__ W2T,
                            float* __restrict__ beta){
  int tid = blockIdx.x * blockDim.x + threadIdx.x;
  int stride = gridDim.x * blockDim.x;
  for (int i = tid; i < 512*256; i += stride){
    int k = i >> 8, n = i & 255;
    WsT[n*512 + k] = f2bf(Ws[i]);
  }
  for (int i = tid; i < 256*256; i += stride){
    int k = i >> 8, n = i & 255;
    W1T[n*256 + k] = f2bf(W1[i]);
    W2T[n*256 + k] = f2bf(W2[i]);
  }
  if (blockIdx.x == 0){
    int j = threadIdx.x;            // 256 threads
    float acc = 0.f;
    for (int l = 0; l < 256; ++l)
      acc = __builtin_fmaf(b2[l], W1[l*256 + j], acc);
    beta[j] = acc;
  }
}

// ---- prep2: MT[j][i] = (W2@W1)[i][j] (fp32 dot, bf16 store) ----
// A-operand for q^T = M^T z^T: A[j][i] = M[i][j]. 256 blocks x 256 threads.
__global__ void prep_mt(const float* __restrict__ W1,
                        const float* __restrict__ W2,
                        __bf16* __restrict__ MT){
  __shared__ float w2row[256];
  const int i = blockIdx.x;
  const int j = threadIdx.x;
  w2row[j] = W2[i*256 + j];
  __syncthreads();
  float acc = 0.f;
  for (int l = 0; l < 256; ++l)
    acc = __builtin_fmaf(w2row[l], W1[l*256 + j], acc);
  MT[j*256 + i] = f2bf(acc);
}

// Fused ODE kernel, round 11: Y-SPACE RECURSION (M = W2@W1 folded).
// Identity: with y = h@W1, each RK4 sub-eval needs only ONE GEMM:
//   q = z_{prev} @ M,  y_eval = y + c*(q + beta),  z = tanh(y_eval + b1 + t*wt)
//   step: y += dt/6 * (q0 + 2q1 + 2q2 + q3 + 6*beta-terms folded into q's)
//   h_T = h0 + (dt/6 * sum(w_i z_i)) @ W2 + b2   (one GEMM at the very end)
// vs r10: HALF the MFMA, HALF the LDS read traffic (one B-matrix/eval),
// HALF the barriers (1/eval), HALF the resident weights (M only, 64 regs).
// Shape: 256 blocks x 64 batch, 512 thr = 8 waves @ 2/SIMD, 32 y-rows/wave.
__global__ __launch_bounds__(512, 2)
void ode_kernel(const float* __restrict__ x,
                const float* __restrict__ b_state,
                const float* __restrict__ W1full,   // 257x256 fp32 (row 256 = t row)
                const float* __restrict__ b1,
                const float* __restrict__ b2,
                const float* __restrict__ Wout,     // 256x18 fp32
                const float* __restrict__ bout,
                const __bf16* __restrict__ WsT,     // [256][512]
                const __bf16* __restrict__ W1Tg,    // [256][256]
                const __bf16* __restrict__ W2Tg,    // [256][256]
                const __bf16* __restrict__ MTg,     // [256][256]
                const float* __restrict__ betag,    // [256]
                float* __restrict__ out)
{
  __shared__ __align__(16) __bf16 lds_sb0[64*SBS];   // 33 KB  z double-buffer A
  __shared__ __align__(16) __bf16 lds_sb1[64*SBS];   // 33 KB  z double-buffer B
  __shared__ __align__(16) __bf16 lds_h0[64*SBS];    // 33 KB  h0 (kept to epilogue)
  __shared__ __align__(16) float  lds_bias[4*256];   //  4 KB  b1 | wt | b2 | beta

  const int tid  = threadIdx.x;
  const int wave = tid >> 6;       // 0..7
  const int lane = tid & 63;
  const int c16  = lane & 15;
  const int q    = lane >> 4;      // 0..3
  const int nh0  = wave * 32;      // this wave's y-row base (32 rows)
  const int m0   = blockIdx.x * 64;

  if (tid < 256){
    lds_bias[tid]       = b1[tid];
    lds_bias[256 + tid] = W1full[256*256 + tid];  // time row of W_dyn1
    lds_bias[512 + tid] = b2[tid];
    lds_bias[768 + tid] = betag[tid];
  }

  // ---- addressing (padded-linear) ----
  int arow[2];
  #pragma unroll
  for (int mt = 0; mt < 2; ++mt) arow[mt] = nh0 + mt*16 + c16;
  const int browc = c16 * SBS;      // B batch-row base (nt adds 16*SBS)
  const int n04   = nh0 + 4*q;      // C/D row base (mt adds 16)
  const int bidx  = n04;

  // ---- resident M fragments (A-operand), 64 regs ----
  bf16x8 Mf[2][8];
  #pragma unroll
  for (int mt = 0; mt < 2; ++mt)
    #pragma unroll
    for (int kt = 0; kt < 8; ++kt)
      Mf[mt][kt] = *(const bf16x8*)&MTg[arow[mt]*256 + kt*32 + q*8];
  #pragma unroll
  for (int mt = 0; mt < 2; ++mt)
    #pragma unroll
    for (int kt = 0; kt < 8; ++kt)
      asm volatile("" : "+v"(Mf[mt][kt]));

  floatx4 y[2][4], p[2][4], sM[2][4], w[2][4];
  const floatx4 vzero = {0.f, 0.f, 0.f, 0.f};
  #pragma unroll
  for (int mt = 0; mt < 2; ++mt)
    #pragma unroll
    for (int nt = 0; nt < 4; ++nt){ sM[mt][nt] = vzero; }

  // ---- phase 0: h0 = tanh(x@Ws + bs) -> lds_h0 ----
  {
    #pragma unroll
    for (int mt = 0; mt < 2; ++mt){
      floatx4 bsv;
      #pragma unroll
      for (int r = 0; r < 4; ++r) bsv[r] = b_state[nh0 + mt*16 + 4*q + r];
      #pragma unroll
      for (int nt = 0; nt < 4; ++nt) p[mt][nt] = bsv;
    }
    #pragma unroll 1
    for (int kt = 0; kt < 16; ++kt){
      bf16x8 b[4];
      #pragma unroll
      for (int nt = 0; nt < 4; ++nt){
        const float* px = &x[(size_t)(m0 + nt*16 + c16)*512 + kt*32 + q*8];
        floatx4 f0 = *(const floatx4*)px;
        floatx4 f1 = *(const floatx4*)(px + 4);
        union { uint32_t u[4]; bf16x8 v; } pk;
        pk.u[0] = cvt_pk_bf16(f0[0], f0[1]);
        pk.u[1] = cvt_pk_bf16(f0[2], f0[3]);
        pk.u[2] = cvt_pk_bf16(f1[0], f1[1]);
        pk.u[3] = cvt_pk_bf16(f1[2], f1[3]);
        b[nt] = pk.v;
      }
      #pragma unroll
      for (int mt = 0; mt < 2; ++mt){
        bf16x8 a = *(const bf16x8*)&WsT[arow[mt]*512 + kt*32 + q*8];
        #pragma unroll
        for (int nt = 0; nt < 4; ++nt)
          p[mt][nt] = __builtin_amdgcn_mfma_f32_16x16x32_bf16(a, b[nt], p[mt][nt], 0, 0, 0);
      }
    }
    #pragma unroll
    for (int mt = 0; mt < 2; ++mt)
      #pragma unroll
      for (int nt = 0; nt < 4; ++nt){
        float v0 = fast_tanh(p[mt][nt][0]);
        float v1 = fast_tanh(p[mt][nt][1]);
        float v2 = fast_tanh(p[mt][nt][2]);
        float v3 = fast_tanh(p[mt][nt][3]);
        uint32x2 wv = { cvt_pk_bf16(v0, v1), cvt_pk_bf16(v2, v3) };
        *(uint32x2*)&lds_h0[browc + nt*(16*SBS) + n04 + mt*16] = wv;
      }
  }
  __syncthreads();

  // ---- y0 = h0 @ W1 (transposed: y^T = W1^T h0^T), W1 frags transient ----
  {
    bf16x8 W1f[2][8];
    #pragma unroll
    for (int mt = 0; mt < 2; ++mt)
      #pragma unroll
      for (int kt = 0; kt < 8; ++kt)
        W1f[mt][kt] = *(const bf16x8*)&W1Tg[arow[mt]*256 + kt*32 + q*8];
    #pragma unroll
    for (int mt = 0; mt < 2; ++mt)
      #pragma unroll
      for (int nt = 0; nt < 4; ++nt) y[mt][nt] = vzero;
    #pragma unroll
    for (int kt = 0; kt < 8; ++kt){
      bf16x8 b[4];
      #pragma unroll
      for (int nt = 0; nt < 4; ++nt)
        b[nt] = *(const bf16x8*)&lds_h0[browc + nt*(16*SBS) + kt*32 + q*8];
      #pragma unroll
      for (int mt = 0; mt < 2; ++mt)
        #pragma unroll
        for (int nt = 0; nt < 4; ++nt)
          y[mt][nt] = __builtin_amdgcn_mfma_f32_16x16x32_bf16(W1f[mt][kt], b[nt], y[mt][nt], 0, 0, 0);
    }
  }

  const float dt  = 1.0f / NSTEPS;
  const float hdt = 0.5f * dt;
  const float dt6 = dt / 6.0f;

  // ---- slot 0: z0 = tanh(y + b1) (t=0), w = z0, write -> SB0 ----
  #pragma unroll
  for (int mt = 0; mt < 2; ++mt){
    floatx4 b1v = *(const floatx4*)&lds_bias[bidx + mt*16];
    #pragma unroll
    for (int nt = 0; nt < 4; ++nt){
      floatx4 zv;
      #pragma unroll
      for (int r = 0; r < 4; ++r) zv[r] = fast_tanh(y[mt][nt][r] + b1v[r]);
      w[mt][nt] = zv;
      uint32x2 wv = { cvt_pk_bf16(zv[0], zv[1]), cvt_pk_bf16(zv[2], zv[3]) };
      *(uint32x2*)&lds_sb0[browc + nt*(16*SBS) + n04 + mt*16] = wv;
    }
  }
  __syncthreads();

  // ---- main loop: slots i = 1..159, ONE GEMM + ONE barrier each ----
  #pragma unroll 1
  for (int i = 1; i < NSTEPS*4; ++i){
    const int e = i & 3;
    const float cin = (e == 0) ? 0.0f : ((e == 3) ? dt : hdt);
    const float te  = dt * (float)(i >> 2) + cin;
    const float wz  = (e == 1 || e == 2) ? 2.0f : 1.0f;
    const __bf16* sbR = ((i & 1) == 1) ? lds_sb0 : lds_sb1;  // holds z_{i-1}
    __bf16*       sbW = ((i & 1) == 1) ? lds_sb1 : lds_sb0;  // gets  z_i

    // GEMM: p = beta + z_{i-1} @ M   (A = M^T resident)
    #pragma unroll
    for (int mt = 0; mt < 2; ++mt){
      floatx4 bev = *(const floatx4*)&lds_bias[768 + bidx + mt*16];
      #pragma unroll
      for (int nt = 0; nt < 4; ++nt) p[mt][nt] = bev;
    }
    #pragma unroll
    for (int kt = 0; kt < 8; ++kt){
      bf16x8 b[4];
      #pragma unroll
      for (int nt = 0; nt < 4; ++nt)
        b[nt] = *(const bf16x8*)&sbR[browc + nt*(16*SBS) + kt*32 + q*8];
      #pragma unroll
      for (int mt = 0; mt < 2; ++mt)
        #pragma unroll
        for (int nt = 0; nt < 4; ++nt)
          p[mt][nt] = __builtin_amdgcn_mfma_f32_16x16x32_bf16(Mf[mt][kt], b[nt], p[mt][nt], 0, 0, 0);
    }

    // RK4 bookkeeping (p = q_{i-1} + beta)
    if (e == 0){
      #pragma unroll
      for (int mt = 0; mt < 2; ++mt)
        #pragma unroll
        for (int nt = 0; nt < 4; ++nt)
          #pragma unroll
          for (int r = 0; r < 4; ++r)
            y[mt][nt][r] = __builtin_fmaf(dt6, sM[mt][nt][r] + p[mt][nt][r], y[mt][nt][r]);
    }
    if (e == 1){
      #pragma unroll
      for (int mt = 0; mt < 2; ++mt)
        #pragma unroll
        for (int nt = 0; nt < 4; ++nt)
          sM[mt][nt] = p[mt][nt];
    } else {
      #pragma unroll
      for (int mt = 0; mt < 2; ++mt)
        #pragma unroll
        for (int nt = 0; nt < 4; ++nt)
          #pragma unroll
          for (int r = 0; r < 4; ++r)
            sM[mt][nt][r] = __builtin_fmaf(2.0f, p[mt][nt][r], sM[mt][nt][r]);
    }

    // z_i = tanh(y + cin*p + b1 + te*wt); w += wz*z; write -> sbW
    #pragma unroll
    for (int mt = 0; mt < 2; ++mt){
      floatx4 b1v = *(const floatx4*)&lds_bias[bidx + mt*16];
      floatx4 wtv = *(const floatx4*)&lds_bias[256 + bidx + mt*16];
      floatx4 bias;
      #pragma unroll
      for (int r = 0; r < 4; ++r) bias[r] = __builtin_fmaf(te, wtv[r], b1v[r]);
      #pragma unroll
      for (int nt = 0; nt < 4; ++nt){
        floatx4 zv;
        #pragma unroll
        for (int r = 0; r < 4; ++r){
          float ye = __builtin_fmaf(cin, p[mt][nt][r], y[mt][nt][r]);
          zv[r] = fast_tanh(ye + bias[r]);
          w[mt][nt][r] = __builtin_fmaf(wz, zv[r], w[mt][nt][r]);
        }
        uint32x2 wv = { cvt_pk_bf16(zv[0], zv[1]), cvt_pk_bf16(zv[2], zv[3]) };
        *(uint32x2*)&sbW[browc + nt*(16*SBS) + n04 + mt*16] = wv;
      }
    }
    __syncthreads();
  }

  // ---- epilogue: h_T = h0 + (dt6*w) @ W2 + b2, then out = h_T @ Wout ----
  // pack dt6*w -> SB0 (z_158 dead; its readers finished before slot-159 barrier)
  #pragma unroll
  for (int mt = 0; mt < 2; ++mt)
    #pragma unroll
    for (int nt = 0; nt < 4; ++nt){
      float v0 = dt6 * w[mt][nt][0];
      float v1 = dt6 * w[mt][nt][1];
      float v2 = dt6 * w[mt][nt][2];
      float v3 = dt6 * w[mt][nt][3];
      uint32x2 wv = { cvt_pk_bf16(v0, v1), cvt_pk_bf16(v2, v3) };
      *(uint32x2*)&lds_sb0[browc + nt*(16*SBS) + n04 + mt*16] = wv;
    }
  __syncthreads();
  {
    bf16x8 W2f[2][8];
    #pragma unroll
    for (int mt = 0; mt < 2; ++mt)
      #pragma unroll
      for (int kt = 0; kt < 8; ++kt)
        W2f[mt][kt] = *(const bf16x8*)&W2Tg[arow[mt]*256 + kt*32 + q*8];
    floatx4 hF[2][4];
    #pragma unroll
    for (int mt = 0; mt < 2; ++mt){
      floatx4 b2v = *(const floatx4*)&lds_bias[512 + bidx + mt*16];
      #pragma unroll
      for (int nt = 0; nt < 4; ++nt) hF[mt][nt] = b2v;
    }
    #pragma unroll
    for (int kt = 0; kt < 8; ++kt){
      bf16x8 b[4];
      #pragma unroll
      for (int nt = 0; nt < 4; ++nt)
        b[nt] = *(const bf16x8*)&lds_sb0[browc + nt*(16*SBS) + kt*32 + q*8];
      #pragma unroll
      for (int mt = 0; mt < 2; ++mt)
        #pragma unroll
        for (int nt = 0; nt < 4; ++nt)
          hF[mt][nt] = __builtin_amdgcn_mfma_f32_16x16x32_bf16(W2f[mt][kt], b[nt], hF[mt][nt], 0, 0, 0);
    }
    // + h0, write h_T -> SB1
    #pragma unroll
    for (int mt = 0; mt < 2; ++mt)
      #pragma unroll
      for (int nt = 0; nt < 4; ++nt){
        bf16x4 h0v = *(const bf16x4*)&lds_h0[browc + nt*(16*SBS) + n04 + mt*16];
        #pragma unroll
        for (int r = 0; r < 4; ++r) hF[mt][nt][r] += bf2f(h0v[r]);
        uint32x2 wv = { cvt_pk_bf16(hF[mt][nt][0], hF[mt][nt][1]),
                        cvt_pk_bf16(hF[mt][nt][2], hF[mt][nt][3]) };
        *(uint32x2*)&lds_sb1[browc + nt*(16*SBS) + n04 + mt*16] = wv;
      }
  }
  __syncthreads();
  {
    const int r  = tid & 63;         // batch row within block
    const int og = tid >> 6;         // 8 groups; first 6 cover 18 outputs
    if (og < 6){
      const int obase = og * 3;
      float acc[3] = {0.f, 0.f, 0.f};
      for (int c = 0; c < 32; ++c){
        bf16x8 h8 = *(const bf16x8*)&lds_sb1[r*SBS + c*8];
        #pragma unroll
        for (int j = 0; j < 8; ++j){
          float hval = bf2f(h8[j]);
          int kk = c*8 + j;
          #pragma unroll
          for (int oo = 0; oo < 3; ++oo)
            acc[oo] += hval * Wout[kk*18 + obase + oo];
        }
      }
      #pragma unroll
      for (int oo = 0; oo < 3; ++oo)
        out[(size_t)(m0 + r)*18 + obase + oo] = acc[oo] + bout[obase + oo];
    }
  }
}

extern "C" void kernel_launch(void* const* d_in, const int* in_sizes, int n_in,
                              void* d_out, int out_size, void* d_ws, size_t ws_size,
                              hipStream_t stream){
  const float* x   = (const float*)d_in[0];
  const float* Ws  = (const float*)d_in[1];
  const float* bs  = (const float*)d_in[2];
  const float* W1  = (const float*)d_in[3];
  const float* b1  = (const float*)d_in[4];
  const float* W2  = (const float*)d_in[5];
  const float* b2  = (const float*)d_in[6];
  const float* Wo  = (const float*)d_in[7];
  const float* bo  = (const float*)d_in[8];
  float* out = (float*)d_out;

  __bf16* WsT  = (__bf16*)d_ws;          // 256x512 bf16 = 256 KB
  __bf16* W1T  = WsT + 512*256;          // 256x256 bf16 = 128 KB
  __bf16* W2T  = W1T + 256*256;          // 256x256 bf16 = 128 KB
  __bf16* MT   = W2T + 256*256;          // 256x256 bf16 = 128 KB
  float*  beta = (float*)(MT + 256*256); // 256 fp32 = 1 KB

  prep_kernel<<<128, 256, 0, stream>>>(Ws, W1, W2, b2, WsT, W1T, W2T, beta);
  prep_mt<<<256, 256, 0, stream>>>(W1, W2, MT);
  ode_kernel<<<256, 512, 0, stream>>>(x, bs, W1, b1, b2, Wo, bo,
                                      WsT, W1T, W2T, MT, beta, out);
}